// Round 3
// baseline (186.508 us; speedup 1.0000x reference)
//
#include <hip/hip_runtime.h>
#include <cstdint>
#include <cstddef>

#define C_DIM 256
#define N_PIX 10000
#define B_SZ 16

// ---------------- k_prep: pos bilinear + posdot (blocks 0..39) | weight transpose ------
// blocks 40..1575: transpose the 6 MLP weight matrices [256][256] -> wT[c][o]
__global__ __launch_bounds__(256) void k_prep(
    const float* __restrict__ pe,
    const float* __restrict__ Wc, const float* __restrict__ Wb,
    const float* __restrict__ dW1, const float* __restrict__ dW2, const float* __restrict__ dW3,
    const float* __restrict__ rW1, const float* __restrict__ rW2, const float* __restrict__ rW3,
    float* __restrict__ posr, float* __restrict__ posdot, float* __restrict__ wT) {
  int tid = threadIdx.x;
  int bid = blockIdx.x;
  if (bid >= 40) {
    // transpose: block -> (matrix m, column c=rem); read W[o][c] for o=tid, write wT
    int t = bid - 40;
    int m = t >> 8;
    int rem = t & 255;
    const float* W;
    switch (m) {
      case 0: W = dW1; break;
      case 1: W = dW2; break;
      case 2: W = dW3; break;
      case 3: W = rW1; break;
      case 4: W = rW2; break;
      default: W = rW3; break;
    }
    wT[(size_t)m * 65536 + (size_t)rem * 256 + tid] = W[(size_t)tid * 256 + rem];
    return;
  }
  // pos-resize + posdot: one pixel per thread, loop all 256 channels
  __shared__ float w[6][C_DIM];
  w[0][tid] = Wc[tid];
  w[1][tid] = Wc[C_DIM + tid];
  w[2][tid] = Wb[tid];
  w[3][tid] = Wb[C_DIM + tid];
  w[4][tid] = Wb[2 * C_DIM + tid];
  w[5][tid] = Wb[3 * C_DIM + tid];
  __syncthreads();
  int n = bid * 256 + tid;
  if (n >= N_PIX) return;
  int y = n / 100, xq = n % 100;
  float sy = fminf(fmaxf((y + 0.5f) * 0.5f - 0.5f, 0.0f), 49.0f);
  float sx = fminf(fmaxf((xq + 0.5f) * 0.5f - 0.5f, 0.0f), 49.0f);
  int y0 = (int)floorf(sy); int y1 = min(y0 + 1, 49); float ty = sy - (float)y0;
  int x0 = (int)floorf(sx); int x1 = min(x0 + 1, 49); float tx = sx - (float)x0;
  float a[6] = {0.f, 0.f, 0.f, 0.f, 0.f, 0.f};
#pragma unroll 4
  for (int c = 0; c < C_DIM; ++c) {
    const float* p = pe + c * 2500;
    float v00 = p[y0 * 50 + x0], v01 = p[y0 * 50 + x1];
    float v10 = p[y1 * 50 + x0], v11 = p[y1 * 50 + x1];
    float r0 = v00 * (1.0f - ty) + v10 * ty;
    float r1 = v01 * (1.0f - ty) + v11 * ty;
    float pv = r0 * (1.0f - tx) + r1 * tx;
    posr[(size_t)c * N_PIX + n] = pv;
#pragma unroll
    for (int o = 0; o < 6; ++o) a[o] = fmaf(w[o][c], pv, a[o]);
  }
#pragma unroll
  for (int o = 0; o < 6; ++o) posdot[o * N_PIX + n] = a[o];
}

// ---------------- fused cls/bbox/conf over x (the 164MB kernel) -------------------------
__global__ __launch_bounds__(256) void k_heads(
    const float* __restrict__ x, const float* __restrict__ posdot,
    const float* __restrict__ Wc, const float* __restrict__ bc,
    const float* __restrict__ Wb, const float* __restrict__ bb,
    float* __restrict__ cls, float* __restrict__ bbox, float* __restrict__ conf) {
  __shared__ float w[6][C_DIM];
  int tid = threadIdx.x;
  w[0][tid] = Wc[tid];
  w[1][tid] = Wc[C_DIM + tid];
  w[2][tid] = Wb[tid];
  w[3][tid] = Wb[C_DIM + tid];
  w[4][tid] = Wb[2 * C_DIM + tid];
  w[5][tid] = Wb[3 * C_DIM + tid];
  __syncthreads();
  int b = blockIdx.y;
  int n0 = blockIdx.x * 512 + tid * 2;
  if (n0 >= N_PIX) return;
  const float* xb = x + (size_t)b * C_DIM * N_PIX + n0;
  float a0x = 0.f, a0y = 0.f, a1x = 0.f, a1y = 0.f, a2x = 0.f, a2y = 0.f;
  float a3x = 0.f, a3y = 0.f, a4x = 0.f, a4y = 0.f, a5x = 0.f, a5y = 0.f;
#pragma unroll 16
  for (int c = 0; c < C_DIM; ++c) {
    float2 xv = *(const float2*)(xb + (size_t)c * N_PIX);
    float w0 = w[0][c], w1 = w[1][c], w2 = w[2][c];
    float w3 = w[3][c], w4 = w[4][c], w5 = w[5][c];
    a0x = fmaf(w0, xv.x, a0x); a0y = fmaf(w0, xv.y, a0y);
    a1x = fmaf(w1, xv.x, a1x); a1y = fmaf(w1, xv.y, a1y);
    a2x = fmaf(w2, xv.x, a2x); a2y = fmaf(w2, xv.y, a2y);
    a3x = fmaf(w3, xv.x, a3x); a3y = fmaf(w3, xv.y, a3y);
    a4x = fmaf(w4, xv.x, a4x); a4y = fmaf(w4, xv.y, a4y);
    a5x = fmaf(w5, xv.x, a5x); a5y = fmaf(w5, xv.y, a5y);
  }
  float2 p0 = *(const float2*)(posdot + 0 * N_PIX + n0);
  float2 p1 = *(const float2*)(posdot + 1 * N_PIX + n0);
  float2 p2 = *(const float2*)(posdot + 2 * N_PIX + n0);
  float2 p3 = *(const float2*)(posdot + 3 * N_PIX + n0);
  float2 p4 = *(const float2*)(posdot + 4 * N_PIX + n0);
  float2 p5 = *(const float2*)(posdot + 5 * N_PIX + n0);
  float bc0 = bc[0], bc1 = bc[1];
  float bb0 = bb[0], bb1 = bb[1], bb2 = bb[2], bb3 = bb[3];
  float c0x = a0x + p0.x + bc0, c0y = a0y + p0.y + bc0;
  float c1x = a1x + p1.x + bc1, c1y = a1y + p1.y + bc1;
  float b0x = a2x + p2.x + bb0, b0y = a2y + p2.y + bb0;
  float b1x = a3x + p3.x + bb1, b1y = a3y + p3.y + bb1;
  float b2x = a4x + p4.x + bb2, b2y = a4y + p4.y + bb2;
  float b3x = a5x + p5.x + bb3, b3y = a5y + p5.y + bb3;
  size_t nb = (size_t)b * N_PIX + n0;
  float4 cv; cv.x = c0x; cv.y = c1x; cv.z = c0y; cv.w = c1y;
  *(float4*)(cls + nb * 2) = cv;
  float4 bv0; bv0.x = b0x; bv0.y = b1x; bv0.z = b2x; bv0.w = b3x;
  float4 bv1; bv1.x = b0y; bv1.y = b1y; bv1.z = b2y; bv1.w = b3y;
  *(float4*)(bbox + nb * 4) = bv0;
  *(float4*)(bbox + nb * 4 + 4) = bv1;
  float m0 = fmaxf(c0x, c1x);
  float e00 = expf(c0x - m0), e10 = expf(c1x - m0);
  float m1 = fmaxf(c0y, c1y);
  float e01 = expf(c0y - m1), e11 = expf(c1y - m1);
  float2 cf; cf.x = e10 / (e00 + e10); cf.y = e11 / (e01 + e11);
  *(float2*)(conf + nb) = cf;
}

// ---------------- per-batch top-100 (radix threshold + bitonic), jax tie-break ----------
// per-wave histograms to avoid LDS same-bin atomic serialization
__global__ __launch_bounds__(1024) void k_topk(const float* __restrict__ conf,
                                               int* __restrict__ idx_out) {
  __shared__ unsigned int ord[N_PIX];
  __shared__ unsigned int whist[16][256];
  __shared__ unsigned int hist[256];
  __shared__ unsigned long long cand[512];
  __shared__ unsigned int s_cnt, s_prefix, s_ncand;
  int tid = threadIdx.x;
  int wv = tid >> 6;
  int b = blockIdx.x;
  const float* cb = conf + (size_t)b * N_PIX;
  for (int i = tid; i < N_PIX; i += 1024) {
    unsigned int u = __float_as_uint(cb[i]);
    ord[i] = (u & 0x80000000u) ? ~u : (u | 0x80000000u);
  }
  unsigned int prefix = 0, cnt_gt = 0;
  for (int pass = 0; pass < 4; ++pass) {
    int sh = 24 - 8 * pass;
    for (int i = tid; i < 16 * 256; i += 1024) ((unsigned int*)whist)[i] = 0;
    __syncthreads();
    unsigned int himask = (pass == 0) ? 0u : (0xFFFFFFFFu << (sh + 8));
    for (int i = tid; i < N_PIX; i += 1024) {
      unsigned int o = ord[i];
      if ((o & himask) == prefix) atomicAdd(&whist[wv][(o >> sh) & 255u], 1u);
    }
    __syncthreads();
    if (tid < 256) {
      unsigned int s = 0;
#pragma unroll
      for (int w2 = 0; w2 < 16; ++w2) s += whist[w2][tid];
      hist[tid] = s;
    }
    __syncthreads();
    if (tid == 0) {
      unsigned int c = cnt_gt; int v = 255;
      while (v > 0 && c + hist[v] < 100u) { c += hist[v]; --v; }
      s_cnt = c; s_prefix = prefix | ((unsigned int)v << sh);
    }
    __syncthreads();
    cnt_gt = s_cnt; prefix = s_prefix;
    __syncthreads();
  }
  if (tid == 0) s_ncand = 0;
  __syncthreads();
  unsigned int T = prefix;
  for (int i = tid; i < N_PIX; i += 1024) {
    unsigned int o = ord[i];
    if (o >= T) {
      unsigned int k = atomicAdd(&s_ncand, 1u);
      if (k < 512u)
        cand[k] = ((unsigned long long)o << 32) |
                  (unsigned long long)(0xFFFFFFFFu - (unsigned int)i);
    }
  }
  __syncthreads();
  unsigned int nc = s_ncand > 512u ? 512u : s_ncand;
  for (int i = tid; i < 512; i += 1024)
    if ((unsigned int)i >= nc) cand[i] = 0ull;
  __syncthreads();
  for (unsigned int k = 2; k <= 512; k <<= 1) {
    for (unsigned int j = k >> 1; j > 0; j >>= 1) {
      if (tid < 512) {
        unsigned int i = (unsigned int)tid, ixj = i ^ j;
        if (ixj > i) {
          unsigned long long a = cand[i], c2 = cand[ixj];
          bool up = ((i & k) == 0);
          if ((a > c2) == up) { cand[i] = c2; cand[ixj] = a; }
        }
      }
      __syncthreads();
    }
  }
  if (tid < 100) {
    unsigned long long key = cand[511 - tid];
    idx_out[b * 100 + tid] = (int)(0xFFFFFFFFu - (unsigned int)(key & 0xFFFFFFFFull));
  }
}

// ---------------- fused gather + 3-layer MLP, R=5 rows/block, coalesced wT loads --------
#define R_ROWS 5

__device__ __forceinline__ void mlp_layerT(const float (*in)[C_DIM], float (*outb)[C_DIM],
    const float* __restrict__ wT, const float* __restrict__ bias, bool relu, int tid) {
  float acc[R_ROWS];
  float bv = bias[tid];
#pragma unroll
  for (int r = 0; r < R_ROWS; ++r) acc[r] = bv;
#pragma unroll 2
  for (int c = 0; c < C_DIM; c += 4) {
    float w0 = wT[(size_t)(c + 0) * C_DIM + tid];
    float w1 = wT[(size_t)(c + 1) * C_DIM + tid];
    float w2 = wT[(size_t)(c + 2) * C_DIM + tid];
    float w3 = wT[(size_t)(c + 3) * C_DIM + tid];
#pragma unroll
    for (int r = 0; r < R_ROWS; ++r) {
      float4 iv = *(const float4*)(&in[r][c]);
      float s = fmaf(w0, iv.x, acc[r]);
      s = fmaf(w1, iv.y, s);
      s = fmaf(w2, iv.z, s);
      acc[r] = fmaf(w3, iv.w, s);
    }
  }
#pragma unroll
  for (int r = 0; r < R_ROWS; ++r) outb[r][tid] = relu ? fmaxf(acc[r], 0.0f) : acc[r];
  __syncthreads();
}

// grid.x = 320 (det: 16 b x 20 chunks) + 80 (rec: 16 b x 5 chunks) = 400
__global__ __launch_bounds__(256) void k_mlp2(
    const float* __restrict__ x, const float* __restrict__ posr, const int* __restrict__ idx,
    const float* __restrict__ wT,
    const float* __restrict__ db1, const float* __restrict__ db2, const float* __restrict__ db3,
    const float* __restrict__ rb1, const float* __restrict__ rb2, const float* __restrict__ rb3,
    const float* __restrict__ det_q, const float* __restrict__ rec_q,
    float* __restrict__ det, float* __restrict__ rec) {
  __shared__ float bufA[R_ROWS][C_DIM];
  __shared__ float bufB[R_ROWS][C_DIM];
  int tid = threadIdx.x;
  int cid = blockIdx.x;
  int b, r0, rpb;
  const float *W1, *B1, *W2, *B2, *W3, *B3, *q;
  float* outp;
  if (cid < 320) {
    b = cid / 20; r0 = (cid % 20) * R_ROWS; rpb = 100;
    W1 = wT; W2 = wT + 65536; W3 = wT + 131072;
    B1 = db1; B2 = db2; B3 = db3;
    q = det_q; outp = det;
  } else {
    int c2 = cid - 320;
    b = c2 / 5; r0 = (c2 % 5) * R_ROWS; rpb = 25;
    W1 = wT + 196608; W2 = wT + 262144; W3 = wT + 327680;
    B1 = rb1; B2 = rb2; B3 = rb3;
    q = rec_q; outp = rec;
  }
  // gather: top-25 is the prefix of top-100, so idx[b*100 + r] works for both parts
#pragma unroll
  for (int r = 0; r < R_ROWS; ++r) {
    int n = idx[b * 100 + r0 + r];
    bufA[r][tid] = x[((size_t)b * C_DIM + tid) * N_PIX + n] +
                   posr[(size_t)tid * N_PIX + n];
  }
  __syncthreads();
  mlp_layerT(bufA, bufB, W1, B1, true, tid);
  mlp_layerT(bufB, bufA, W2, B2, true, tid);
  mlp_layerT(bufA, bufB, W3, B3, false, tid);
#pragma unroll
  for (int r = 0; r < R_ROWS; ++r) {
    int rr = r0 + r;
    outp[((size_t)b * rpb + rr) * C_DIM + tid] = bufB[r][tid] + q[rr * C_DIM + tid];
  }
}

extern "C" void kernel_launch(void* const* d_in, const int* in_sizes, int n_in,
                              void* d_out, int out_size, void* d_ws, size_t ws_size,
                              hipStream_t stream) {
  const float* x     = (const float*)d_in[0];
  const float* Wc    = (const float*)d_in[1];
  const float* bc    = (const float*)d_in[2];
  const float* Wb    = (const float*)d_in[3];
  const float* bb    = (const float*)d_in[4];
  const float* dW1   = (const float*)d_in[5];
  const float* db1   = (const float*)d_in[6];
  const float* dW2   = (const float*)d_in[7];
  const float* db2   = (const float*)d_in[8];
  const float* dW3   = (const float*)d_in[9];
  const float* db3   = (const float*)d_in[10];
  const float* rW1   = (const float*)d_in[11];
  const float* rb1   = (const float*)d_in[12];
  const float* rW2   = (const float*)d_in[13];
  const float* rb2   = (const float*)d_in[14];
  const float* rW3   = (const float*)d_in[15];
  const float* rb3   = (const float*)d_in[16];
  const float* det_q = (const float*)d_in[17];
  const float* rec_q = (const float*)d_in[18];
  const float* pos_e = (const float*)d_in[19];

  float* out  = (float*)d_out;
  float* det  = out;                // [16,100,256]  409600
  float* rec  = out + 409600;       // [16, 25,256]  102400
  float* cls  = out + 512000;       // [16,10000,2]  320000
  float* bbox = out + 832000;       // [16,10000,4]  640000

  // ws layout (floats): posr 2.56e6 | posdot 61440 | conf 160000 | idx 2048(int) | wT 6*65536
  float* posr   = (float*)d_ws;
  float* posdot = posr + 2560000;
  float* conf   = posdot + 61440;
  int*   idx    = (int*)(conf + 160000);
  float* wT     = conf + 160000 + 2048;

  k_prep<<<40 + 1536, 256, 0, stream>>>(pos_e, Wc, Wb, dW1, dW2, dW3, rW1, rW2, rW3,
                                        posr, posdot, wT);
  k_heads<<<dim3(20, B_SZ), 256, 0, stream>>>(x, posdot, Wc, bc, Wb, bb, cls, bbox, conf);
  k_topk<<<B_SZ, 1024, 0, stream>>>(conf, idx);
  k_mlp2<<<400, 256, 0, stream>>>(x, posr, idx, wT,
                                  db1, db2, db3, rb1, rb2, rb3,
                                  det_q, rec_q, det, rec);
}

// Round 4
// 153.849 us; speedup vs baseline: 1.2123x; 1.2123x over previous
//
#include <hip/hip_runtime.h>
#include <cstdint>
#include <cstddef>

#define C_DIM 256
#define N_PIX 10000
#define B_SZ 16

// ---------------- k_wpe: wpe[o][p] = sum_c W[o][c] * pe[c][p]  (o: cls0,cls1,bb0..3) ----
__global__ __launch_bounds__(256) void k_wpe(const float* __restrict__ pe,
    const float* __restrict__ Wc, const float* __restrict__ Wb, float* __restrict__ wpe) {
  int p = blockIdx.x * 256 + threadIdx.x;   // grid (10, 6)
  int o = blockIdx.y;
  if (p >= 2500) return;
  const float* W = (o < 2) ? (Wc + o * C_DIM) : (Wb + (o - 2) * C_DIM);
  float acc = 0.f;
#pragma unroll 8
  for (int c = 0; c < C_DIM; ++c) acc = fmaf(W[c], pe[c * 2500 + p], acc);
  wpe[o * 2500 + p] = acc;
}

// ---------------- fused cls/bbox/conf over x (the 164MB kernel), 1 px/thread ------------
__global__ __launch_bounds__(256, 4) void k_heads(
    const float* __restrict__ x, const float* __restrict__ wpe,
    const float* __restrict__ Wc, const float* __restrict__ bc,
    const float* __restrict__ Wb, const float* __restrict__ bb,
    float* __restrict__ cls, float* __restrict__ bbox, float* __restrict__ conf) {
  __shared__ float w[6][C_DIM];
  int tid = threadIdx.x;
  w[0][tid] = Wc[tid];
  w[1][tid] = Wc[C_DIM + tid];
  w[2][tid] = Wb[tid];
  w[3][tid] = Wb[C_DIM + tid];
  w[4][tid] = Wb[2 * C_DIM + tid];
  w[5][tid] = Wb[3 * C_DIM + tid];
  __syncthreads();
  int b = blockIdx.y;
  int n = blockIdx.x * 256 + tid;            // grid (40, 16)
  if (n >= N_PIX) return;
  const float* xb = x + (size_t)b * C_DIM * N_PIX + n;
  float a0 = 0.f, a1 = 0.f, a2 = 0.f, a3 = 0.f, a4 = 0.f, a5 = 0.f;
#pragma unroll 4
  for (int c = 0; c < C_DIM; c += 4) {
    float x0 = xb[(size_t)(c + 0) * N_PIX];
    float x1 = xb[(size_t)(c + 1) * N_PIX];
    float x2 = xb[(size_t)(c + 2) * N_PIX];
    float x3 = xb[(size_t)(c + 3) * N_PIX];
    float4 w0 = *(const float4*)(&w[0][c]);
    float4 w1 = *(const float4*)(&w[1][c]);
    float4 w2 = *(const float4*)(&w[2][c]);
    float4 w3 = *(const float4*)(&w[3][c]);
    float4 w4 = *(const float4*)(&w[4][c]);
    float4 w5 = *(const float4*)(&w[5][c]);
    a0 = fmaf(w0.x, x0, a0); a0 = fmaf(w0.y, x1, a0); a0 = fmaf(w0.z, x2, a0); a0 = fmaf(w0.w, x3, a0);
    a1 = fmaf(w1.x, x0, a1); a1 = fmaf(w1.y, x1, a1); a1 = fmaf(w1.z, x2, a1); a1 = fmaf(w1.w, x3, a1);
    a2 = fmaf(w2.x, x0, a2); a2 = fmaf(w2.y, x1, a2); a2 = fmaf(w2.z, x2, a2); a2 = fmaf(w2.w, x3, a2);
    a3 = fmaf(w3.x, x0, a3); a3 = fmaf(w3.y, x1, a3); a3 = fmaf(w3.z, x2, a3); a3 = fmaf(w3.w, x3, a3);
    a4 = fmaf(w4.x, x0, a4); a4 = fmaf(w4.y, x1, a4); a4 = fmaf(w4.z, x2, a4); a4 = fmaf(w4.w, x3, a4);
    a5 = fmaf(w5.x, x0, a5); a5 = fmaf(w5.y, x1, a5); a5 = fmaf(w5.z, x2, a5); a5 = fmaf(w5.w, x3, a5);
  }
  // inline posdot: bilinear interp of wpe at pixel n (wpe is 60KB, L1/L2-hot)
  int y = n / 100, xq = n % 100;
  float sy = fminf(fmaxf((y + 0.5f) * 0.5f - 0.5f, 0.0f), 49.0f);
  float sx = fminf(fmaxf((xq + 0.5f) * 0.5f - 0.5f, 0.0f), 49.0f);
  int y0 = (int)floorf(sy); int y1 = min(y0 + 1, 49); float ty = sy - (float)y0;
  int x0i = (int)floorf(sx); int x1i = min(x0i + 1, 49); float tx = sx - (float)x0i;
  float pd[6];
#pragma unroll
  for (int o = 0; o < 6; ++o) {
    const float* m = wpe + o * 2500;
    float v00 = m[y0 * 50 + x0i], v01 = m[y0 * 50 + x1i];
    float v10 = m[y1 * 50 + x0i], v11 = m[y1 * 50 + x1i];
    float r0 = v00 * (1.0f - ty) + v10 * ty;
    float r1 = v01 * (1.0f - ty) + v11 * ty;
    pd[o] = r0 * (1.0f - tx) + r1 * tx;
  }
  float c0 = a0 + pd[0] + bc[0];
  float c1 = a1 + pd[1] + bc[1];
  float b0 = a2 + pd[2] + bb[0];
  float b1 = a3 + pd[3] + bb[1];
  float b2 = a4 + pd[4] + bb[2];
  float b3 = a5 + pd[5] + bb[3];
  size_t nb = (size_t)b * N_PIX + n;
  float2 cv; cv.x = c0; cv.y = c1;
  *(float2*)(cls + nb * 2) = cv;
  float4 bv; bv.x = b0; bv.y = b1; bv.z = b2; bv.w = b3;
  *(float4*)(bbox + nb * 4) = bv;
  float m0 = fmaxf(c0, c1);
  float e0 = expf(c0 - m0), e1 = expf(c1 - m0);
  conf[nb] = e1 / (e0 + e1);
}

// ---------------- per-batch top-100 (radix threshold + bitonic), jax tie-break ----------
__global__ __launch_bounds__(1024) void k_topk(const float* __restrict__ conf,
                                               int* __restrict__ idx_out) {
  __shared__ unsigned int ord[N_PIX];
  __shared__ unsigned int whist[16][256];
  __shared__ unsigned int hist[256];
  __shared__ unsigned long long cand[512];
  __shared__ unsigned int s_cnt, s_prefix, s_ncand;
  int tid = threadIdx.x;
  int wv = tid >> 6;
  int b = blockIdx.x;
  const float* cb = conf + (size_t)b * N_PIX;
  for (int i = tid; i < N_PIX; i += 1024) {
    unsigned int u = __float_as_uint(cb[i]);
    ord[i] = (u & 0x80000000u) ? ~u : (u | 0x80000000u);
  }
  unsigned int prefix = 0, cnt_gt = 0;
  for (int pass = 0; pass < 4; ++pass) {
    int sh = 24 - 8 * pass;
    for (int i = tid; i < 16 * 256; i += 1024) ((unsigned int*)whist)[i] = 0;
    __syncthreads();
    unsigned int himask = (pass == 0) ? 0u : (0xFFFFFFFFu << (sh + 8));
    for (int i = tid; i < N_PIX; i += 1024) {
      unsigned int o = ord[i];
      if ((o & himask) == prefix) atomicAdd(&whist[wv][(o >> sh) & 255u], 1u);
    }
    __syncthreads();
    if (tid < 256) {
      unsigned int s = 0;
#pragma unroll
      for (int w2 = 0; w2 < 16; ++w2) s += whist[w2][tid];
      hist[tid] = s;
    }
    __syncthreads();
    if (tid == 0) {
      unsigned int c = cnt_gt; int v = 255;
      while (v > 0 && c + hist[v] < 100u) { c += hist[v]; --v; }
      s_cnt = c; s_prefix = prefix | ((unsigned int)v << sh);
    }
    __syncthreads();
    cnt_gt = s_cnt; prefix = s_prefix;
    __syncthreads();
  }
  if (tid == 0) s_ncand = 0;
  __syncthreads();
  unsigned int T = prefix;
  for (int i = tid; i < N_PIX; i += 1024) {
    unsigned int o = ord[i];
    if (o >= T) {
      unsigned int k = atomicAdd(&s_ncand, 1u);
      if (k < 512u)
        cand[k] = ((unsigned long long)o << 32) |
                  (unsigned long long)(0xFFFFFFFFu - (unsigned int)i);
    }
  }
  __syncthreads();
  unsigned int nc = s_ncand > 512u ? 512u : s_ncand;
  for (int i = tid; i < 512; i += 1024)
    if ((unsigned int)i >= nc) cand[i] = 0ull;
  __syncthreads();
  for (unsigned int k = 2; k <= 512; k <<= 1) {
    for (unsigned int j = k >> 1; j > 0; j >>= 1) {
      if (tid < 512) {
        unsigned int i = (unsigned int)tid, ixj = i ^ j;
        if (ixj > i) {
          unsigned long long a = cand[i], c2 = cand[ixj];
          bool up = ((i & k) == 0);
          if ((a > c2) == up) { cand[i] = c2; cand[ixj] = a; }
        }
      }
      __syncthreads();
    }
  }
  if (tid < 100) {
    unsigned long long key = cand[511 - tid];
    idx_out[b * 100 + tid] = (int)(0xFFFFFFFFu - (unsigned int)(key & 0xFFFFFFFFull));
  }
}

// ---------------- fused gather (+inline pos) + 3-layer MLP, R=5 rows/block --------------
#define R_ROWS 5

__device__ __forceinline__ void mlp_layer5(const float (*in)[C_DIM], float (*outb)[C_DIM],
    const float* __restrict__ W, const float* __restrict__ bias, bool relu, int tid) {
  float acc[R_ROWS];
  float bv = bias[tid];
#pragma unroll
  for (int r = 0; r < R_ROWS; ++r) acc[r] = bv;
  const float* wrow = W + (size_t)tid * C_DIM;
#pragma unroll 4
  for (int c = 0; c < C_DIM; c += 4) {
    float4 w4 = *(const float4*)(wrow + c);
#pragma unroll
    for (int r = 0; r < R_ROWS; ++r) {
      float4 iv = *(const float4*)(&in[r][c]);
      float s = fmaf(w4.x, iv.x, acc[r]);
      s = fmaf(w4.y, iv.y, s);
      s = fmaf(w4.z, iv.z, s);
      acc[r] = fmaf(w4.w, iv.w, s);
    }
  }
#pragma unroll
  for (int r = 0; r < R_ROWS; ++r) outb[r][tid] = relu ? fmaxf(acc[r], 0.0f) : acc[r];
  __syncthreads();
}

// grid.x = 320 (det: 16 b x 20 chunks) + 80 (rec: 16 b x 5 chunks) = 400
__global__ __launch_bounds__(256) void k_mlp2(
    const float* __restrict__ x, const float* __restrict__ pe, const int* __restrict__ idx,
    const float* __restrict__ dW1, const float* __restrict__ db1,
    const float* __restrict__ dW2, const float* __restrict__ db2,
    const float* __restrict__ dW3, const float* __restrict__ db3,
    const float* __restrict__ rW1, const float* __restrict__ rb1,
    const float* __restrict__ rW2, const float* __restrict__ rb2,
    const float* __restrict__ rW3, const float* __restrict__ rb3,
    const float* __restrict__ det_q, const float* __restrict__ rec_q,
    float* __restrict__ det, float* __restrict__ rec) {
  __shared__ float bufA[R_ROWS][C_DIM];
  __shared__ float bufB[R_ROWS][C_DIM];
  int tid = threadIdx.x;
  int cid = blockIdx.x;
  int b, r0, rpb;
  const float *W1, *B1, *W2, *B2, *W3, *B3, *q;
  float* outp;
  if (cid < 320) {
    b = cid / 20; r0 = (cid % 20) * R_ROWS; rpb = 100;
    W1 = dW1; B1 = db1; W2 = dW2; B2 = db2; W3 = dW3; B3 = db3;
    q = det_q; outp = det;
  } else {
    int c2 = cid - 320;
    b = c2 / 5; r0 = (c2 % 5) * R_ROWS; rpb = 25;
    W1 = rW1; B1 = rb1; W2 = rW2; B2 = rb2; W3 = rW3; B3 = rb3;
    q = rec_q; outp = rec;
  }
  // gather x + recomputed pos (bilinear of pe at selected pixel), c = tid
#pragma unroll
  for (int r = 0; r < R_ROWS; ++r) {
    int n = idx[b * 100 + r0 + r];
    int y = n / 100, xq = n % 100;
    float sy = fminf(fmaxf((y + 0.5f) * 0.5f - 0.5f, 0.0f), 49.0f);
    float sx = fminf(fmaxf((xq + 0.5f) * 0.5f - 0.5f, 0.0f), 49.0f);
    int y0 = (int)floorf(sy); int y1 = min(y0 + 1, 49); float ty = sy - (float)y0;
    int x0i = (int)floorf(sx); int x1i = min(x0i + 1, 49); float tx = sx - (float)x0i;
    const float* p = pe + tid * 2500;
    float v00 = p[y0 * 50 + x0i], v01 = p[y0 * 50 + x1i];
    float v10 = p[y1 * 50 + x0i], v11 = p[y1 * 50 + x1i];
    float rr0 = v00 * (1.0f - ty) + v10 * ty;
    float rr1 = v01 * (1.0f - ty) + v11 * ty;
    float pv = rr0 * (1.0f - tx) + rr1 * tx;
    bufA[r][tid] = x[((size_t)b * C_DIM + tid) * N_PIX + n] + pv;
  }
  __syncthreads();
  mlp_layer5(bufA, bufB, W1, B1, true, tid);
  mlp_layer5(bufB, bufA, W2, B2, true, tid);
  mlp_layer5(bufA, bufB, W3, B3, false, tid);
#pragma unroll
  for (int r = 0; r < R_ROWS; ++r) {
    int rr = r0 + r;
    outp[((size_t)b * rpb + rr) * C_DIM + tid] = bufB[r][tid] + q[rr * C_DIM + tid];
  }
}

extern "C" void kernel_launch(void* const* d_in, const int* in_sizes, int n_in,
                              void* d_out, int out_size, void* d_ws, size_t ws_size,
                              hipStream_t stream) {
  const float* x     = (const float*)d_in[0];
  const float* Wc    = (const float*)d_in[1];
  const float* bc    = (const float*)d_in[2];
  const float* Wb    = (const float*)d_in[3];
  const float* bb    = (const float*)d_in[4];
  const float* dW1   = (const float*)d_in[5];
  const float* db1   = (const float*)d_in[6];
  const float* dW2   = (const float*)d_in[7];
  const float* db2   = (const float*)d_in[8];
  const float* dW3   = (const float*)d_in[9];
  const float* db3   = (const float*)d_in[10];
  const float* rW1   = (const float*)d_in[11];
  const float* rb1   = (const float*)d_in[12];
  const float* rW2   = (const float*)d_in[13];
  const float* rb2   = (const float*)d_in[14];
  const float* rW3   = (const float*)d_in[15];
  const float* rb3   = (const float*)d_in[16];
  const float* det_q = (const float*)d_in[17];
  const float* rec_q = (const float*)d_in[18];
  const float* pos_e = (const float*)d_in[19];

  float* out  = (float*)d_out;
  float* det  = out;                // [16,100,256]  409600
  float* rec  = out + 409600;       // [16, 25,256]  102400
  float* cls  = out + 512000;       // [16,10000,2]  320000
  float* bbox = out + 832000;       // [16,10000,4]  640000

  // ws layout (floats): conf 160000 | idx 2048 (ints) | wpe 15000
  float* conf = (float*)d_ws;
  int*   idx  = (int*)(conf + 160000);
  float* wpe  = (float*)(idx + 2048);

  k_wpe<<<dim3(10, 6), 256, 0, stream>>>(pos_e, Wc, Wb, wpe);
  k_heads<<<dim3(40, B_SZ), 256, 0, stream>>>(x, wpe, Wc, bc, Wb, bb, cls, bbox, conf);
  k_topk<<<B_SZ, 1024, 0, stream>>>(conf, idx);
  k_mlp2<<<400, 256, 0, stream>>>(x, pos_e, idx,
                                  dW1, db1, dW2, db2, dW3, db3,
                                  rW1, rb1, rW2, rb2, rW3, rb3,
                                  det_q, rec_q, det, rec);
}